// Round 14
// baseline (1030.680 us; speedup 1.0000x reference)
//
#include <hip/hip_runtime.h>
#include <hip/hip_bf16.h>

#define NFEAT 256

typedef __attribute__((ext_vector_type(8))) short bf16x8;   // MFMA A/B frag (4 VGPRs)
typedef __attribute__((ext_vector_type(4))) float f32x4;    // MFMA C/D frag
typedef __attribute__((ext_vector_type(8))) unsigned short us8;

__device__ __forceinline__ float bf2f(unsigned short u) {
    union { unsigned int i; float f; } v; v.i = ((unsigned int)u) << 16; return v.f;
}

__device__ __forceinline__ void f2hilo(float x, unsigned short& h, unsigned short& l) {
    __hip_bfloat16 hb = __float2bfloat16(x);          // RNE
    float hf = __bfloat162float(hb);
    __hip_bfloat16 lb = __float2bfloat16(x - hf);
    h = *reinterpret_cast<unsigned short*>(&hb);
    l = *reinterpret_cast<unsigned short*>(&lb);
}

// LDS granule layout: element (row r, kk in 32-step) -> granule (r>>4)*64+(kk>>3)*16+(r&15), elem kk&7.

// ---------------- weight conversion (transposed [N][K] split planes) ----------------
__global__ __launch_bounds__(256) void cvt8_kernel(
    const float* w0, const float* w1, const float* w2, const float* w3,
    const float* w4, const float* w5, const float* w6, const float* w7,
    unsigned short* base)
{
    int wi = blockIdx.y;
    const float* W = (wi==0)?w0:(wi==1)?w1:(wi==2)?w2:(wi==3)?w3:
                     (wi==4)?w4:(wi==5)?w5:(wi==6)?w6:w7;
    int idx = blockIdx.x * 256 + threadIdx.x;     // 0..65535
    int k = idx >> 8, c = idx & 255;
    unsigned short h, l;
    f2hilo(W[idx], h, l);
    unsigned short* Th = base + (size_t)wi * 131072;
    Th[c * 256 + k] = h;
    Th[65536 + c * 256 + k] = l;
}

__global__ __launch_bounds__(256) void cvtfold_kernel(
    const float* a0, const float* a1, const float* a2,
    const float* b0, const float* b1, const float* b2,
    unsigned short* base)
{
    int wi = blockIdx.y;
    int idx = blockIdx.x * 256 + threadIdx.x;
    float v = wi ? (b0[idx] + b1[idx] + b2[idx]) : (a0[idx] + a1[idx] + a2[idx]);
    int k = idx >> 8, c = idx & 255;
    unsigned short h, l;
    f2hilo(v, h, l);
    unsigned short* Th = base + (size_t)(8 + wi) * 131072;
    Th[c * 256 + k] = h;
    Th[65536 + c * 256 + k] = l;
}

__global__ __launch_bounds__(256) void cvtrect_kernel(const float* W, unsigned short* base) {
    int idx = blockIdx.x * 256 + threadIdx.x;     // 0..32767
    if (idx >= 256 * 128) return;
    int k = idx >> 7, c = idx & 127;
    unsigned short h, l;
    f2hilo(W[idx], h, l);
    unsigned short* Th = base + (size_t)10 * 131072;
    Th[c * 256 + k] = h;
    Th[65536 + c * 256 + k] = l;
}

// ---------------- CSR build ----------------
__global__ __launch_bounds__(256) void deg_int_kernel(const int* __restrict__ dst,
                                                      int* __restrict__ deg, int nE) {
    int e = blockIdx.x * 256 + threadIdx.x;
    if (e < nE) atomicAdd(&deg[dst[e]], 1);
}

__global__ __launch_bounds__(256) void scan_p1(const int* __restrict__ deg, int n,
                                               int* __restrict__ off, int* __restrict__ bsum) {
    __shared__ int tmp[256];
    int tid = threadIdx.x;
    int i = blockIdx.x * 256 + tid;
    tmp[tid] = (i < n) ? deg[i] : 0;
    __syncthreads();
    #pragma unroll
    for (int ofs = 1; ofs < 256; ofs <<= 1) {
        int t = (tid >= ofs) ? tmp[tid - ofs] : 0;
        __syncthreads();
        tmp[tid] += t;
        __syncthreads();
    }
    if (i < n) off[i + 1] = tmp[tid];
    if (tid == 255) bsum[blockIdx.x] = tmp[255];
}

__global__ __launch_bounds__(256) void scan_p2(int* __restrict__ bA, int nA,
                                               int* __restrict__ bB, int nB,
                                               int* __restrict__ bC, int nC) {
    int* bs; int nb;
    if (blockIdx.x == 0) { bs = bA; nb = nA; }
    else if (blockIdx.x == 1) { bs = bB; nb = nB; }
    else { bs = bC; nb = nC; }
    __shared__ int tmp[256];
    int tid = threadIdx.x;
    tmp[tid] = (tid < nb) ? bs[tid] : 0;
    __syncthreads();
    #pragma unroll
    for (int ofs = 1; ofs < 256; ofs <<= 1) {
        int t = (tid >= ofs) ? tmp[tid - ofs] : 0;
        __syncthreads();
        tmp[tid] += t;
        __syncthreads();
    }
    if (tid < nb) bs[tid] = tmp[tid];
}

__global__ __launch_bounds__(256) void scan_p3(int n, int* __restrict__ off,
                                               const int* __restrict__ bsum) {
    int i = blockIdx.x * 256 + threadIdx.x;
    if (i == 0) off[0] = 0;
    if (i >= n) return;
    int b = blockIdx.x;
    if (b > 0) off[i + 1] += bsum[b - 1];
}

__global__ __launch_bounds__(256) void fill_csr_kernel(const int* __restrict__ src,
                                                       const int* __restrict__ dst, int nE,
                                                       const int* __restrict__ off,
                                                       int* __restrict__ cursor,
                                                       int* __restrict__ list) {
    int e = blockIdx.x * 256 + threadIdx.x;
    if (e >= nE) return;
    int d = dst[e];
    int pos = atomicAdd(&cursor[d], 1);
    list[off[d] + pos] = src[e];
}

// ---------------- aggregation (gather, no atomics; plane-pair output) ----------------
// src: fp32 (Tf) or planes (Th/Tl). optional add-in planes (AccH/AccL, may alias dst).
__global__ __launch_bounds__(256) void agg_csr(
    const float* __restrict__ Tf,
    const unsigned short* __restrict__ Th, const unsigned short* __restrict__ Tl,
    const int* __restrict__ off, const int* __restrict__ list,
    const unsigned short* __restrict__ AccH, const unsigned short* __restrict__ AccL,
    unsigned short* __restrict__ Dh, unsigned short* __restrict__ Dl,
    int do_relu, int M)
{
    int r = blockIdx.x * 4 + (threadIdx.x >> 6);
    if (r >= M) return;
    int lane = threadIdx.x & 63;
    int start = off[r], end = off[r + 1];
    float4 acc = make_float4(0.f, 0.f, 0.f, 0.f);
    for (int e = start; e < end; ++e) {
        int s = list[e];
        float4 v;
        if (Tf) {
            v = ((const float4*)(Tf + (size_t)s * NFEAT))[lane];
        } else {
            ushort4 h4 = ((const ushort4*)(Th + (size_t)s * NFEAT))[lane];
            ushort4 l4 = ((const ushort4*)(Tl + (size_t)s * NFEAT))[lane];
            v.x = bf2f(h4.x) + bf2f(l4.x);
            v.y = bf2f(h4.y) + bf2f(l4.y);
            v.z = bf2f(h4.z) + bf2f(l4.z);
            v.w = bf2f(h4.w) + bf2f(l4.w);
        }
        acc.x += v.x; acc.y += v.y; acc.z += v.z; acc.w += v.w;
    }
    int cnt = end - start;
    float inv = (cnt > 0) ? 1.0f / (float)cnt : 0.0f;
    float4 d;
    d.x = acc.x * inv; d.y = acc.y * inv;
    d.z = acc.z * inv; d.w = acc.w * inv;
    if (AccH) {
        ushort4 ah = ((const ushort4*)(AccH + (size_t)r * NFEAT))[lane];
        ushort4 al = ((const ushort4*)(AccL + (size_t)r * NFEAT))[lane];
        d.x += bf2f(ah.x) + bf2f(al.x);
        d.y += bf2f(ah.y) + bf2f(al.y);
        d.z += bf2f(ah.z) + bf2f(al.z);
        d.w += bf2f(ah.w) + bf2f(al.w);
    }
    if (do_relu) {
        d.x = fmaxf(d.x, 0.f); d.y = fmaxf(d.y, 0.f);
        d.z = fmaxf(d.z, 0.f); d.w = fmaxf(d.w, 0.f);
    }
    ushort4 oh, ol;
    f2hilo(d.x, oh.x, ol.x);
    f2hilo(d.y, oh.y, ol.y);
    f2hilo(d.z, oh.z, ol.z);
    f2hilo(d.w, oh.w, ol.w);
    ((ushort4*)(Dh + (size_t)r * NFEAT))[lane] = oh;
    ((ushort4*)(Dl + (size_t)r * NFEAT))[lane] = ol;
}

// ---------------- alpha ----------------
__global__ __launch_bounds__(256) void alpha_kernel(const float* __restrict__ s0,
                                                    const float* __restrict__ s1,
                                                    float* __restrict__ alpha, int M) {
    int n = blockIdx.x * 256 + threadIdx.x;
    if (n >= M) return;
    float v0 = s0[n], v1 = s1[n];
    float m = fmaxf(v0, v1);
    float e0 = expf(v0 - m), e1 = expf(v1 - m);
    float inv = 1.0f / (e0 + e1);
    alpha[n]     = e0 * inv;
    alpha[M + n] = e1 * inv;
}

// ---------------- multi-segment split-bf16 MFMA GEMM (R13 schedule, plane A inputs) ----------------
// per-seg A: fp32 (Af; convert in staging) or pre-split planes (Ahp/Alp; pure copy).
// Output always plane pair Ch/Cl.
struct SegA {
    const float* Af;
    const unsigned short* Ahp;
    const unsigned short* Alp;
    const unsigned short* Wh;
    const unsigned short* Wl;
};

__global__ __launch_bounds__(256, 2) void gemm_ms(
    SegA sa0, SegA sa1, SegA sa2, int nseg,
    const float* __restrict__ bias, int do_relu,
    unsigned short* __restrict__ Ch, unsigned short* __restrict__ Cl,
    int M, int N)
{
    __shared__ unsigned short Ah[128 * 32];
    __shared__ unsigned short Al[128 * 32];
    __shared__ unsigned short Bh[128 * 32];
    __shared__ unsigned short Bl[128 * 32];

    int tid = threadIdx.x;
    int lane = tid & 63;
    int w = tid >> 6;
    int wr = w >> 1, wc = w & 1;
    int row0 = blockIdx.x * 128, col0 = blockIdx.y * 128;
    int fr = lane & 15;
    int fg = lane >> 4;

    int sr = tid >> 1;            // staging row/col 0..127
    int sk = (tid & 1) * 16;      // k offset 0/16
    int grow = row0 + sr; if (grow >= M) grow = M - 1;
    int gcol = col0 + sr;
    int wbase = ((sr >> 4) * 64 + (sk >> 3) * 16 + (sr & 15)) * 8;

    f32x4 acc[4][4];
    #pragma unroll
    for (int m = 0; m < 4; ++m)
        #pragma unroll
        for (int n = 0; n < 4; ++n)
            acc[m][n] = (f32x4)(0.f);

    for (int s = 0; s < 3; ++s) {
        if (s >= nseg) break;
        SegA sg = (s == 0) ? sa0 : (s == 1) ? sa1 : sa2;
        const unsigned short* WhR = sg.Wh + (size_t)gcol * NFEAT;
        const unsigned short* WlR = sg.Wl + (size_t)gcol * NFEAT;

        for (int k0 = 0; k0 < NFEAT; k0 += 32) {
            us8 ah0, ah1, al0, al1;
            if (sg.Af) {
                const float* Xrow = sg.Af + (size_t)grow * NFEAT + k0 + sk;
                unsigned short hh[16], ll[16];
                #pragma unroll
                for (int q = 0; q < 4; ++q) {
                    float4 v = *(const float4*)(Xrow + q * 4);
                    f2hilo(v.x, hh[q*4+0], ll[q*4+0]);
                    f2hilo(v.y, hh[q*4+1], ll[q*4+1]);
                    f2hilo(v.z, hh[q*4+2], ll[q*4+2]);
                    f2hilo(v.w, hh[q*4+3], ll[q*4+3]);
                }
                ah0 = *(us8*)&hh[0]; ah1 = *(us8*)&hh[8];
                al0 = *(us8*)&ll[0]; al1 = *(us8*)&ll[8];
            } else {
                const unsigned short* XH = sg.Ahp + (size_t)grow * NFEAT + k0 + sk;
                const unsigned short* XL = sg.Alp + (size_t)grow * NFEAT + k0 + sk;
                ah0 = *(const us8*)XH;       ah1 = *(const us8*)(XH + 8);
                al0 = *(const us8*)XL;       al1 = *(const us8*)(XL + 8);
            }
            us8 bh0 = *(const us8*)(WhR + k0 + sk);
            us8 bh1 = *(const us8*)(WhR + k0 + sk + 8);
            us8 bl0 = *(const us8*)(WlR + k0 + sk);
            us8 bl1 = *(const us8*)(WlR + k0 + sk + 8);
            __syncthreads();
            *(us8*)&Ah[wbase]       = ah0;
            *(us8*)&Ah[wbase + 128] = ah1;
            *(us8*)&Al[wbase]       = al0;
            *(us8*)&Al[wbase + 128] = al1;
            *(us8*)&Bh[wbase]       = bh0;
            *(us8*)&Bh[wbase + 128] = bh1;
            *(us8*)&Bl[wbase]       = bl0;
            *(us8*)&Bl[wbase + 128] = bl1;
            __syncthreads();

            bf16x8 ahf[4], alf[4], bhf[4], blf[4];
            #pragma unroll
            for (int m = 0; m < 4; ++m) {
                int g = ((wr * 4 + m) * 64 + lane) * 8;
                ahf[m] = *(const bf16x8*)&Ah[g];
                alf[m] = *(const bf16x8*)&Al[g];
            }
            #pragma unroll
            for (int n = 0; n < 4; ++n) {
                int g = ((wc * 4 + n) * 64 + lane) * 8;
                bhf[n] = *(const bf16x8*)&Bh[g];
                blf[n] = *(const bf16x8*)&Bl[g];
            }
            #pragma unroll
            for (int m = 0; m < 4; ++m)
                #pragma unroll
                for (int n = 0; n < 4; ++n) {
                    acc[m][n] = __builtin_amdgcn_mfma_f32_16x16x32_bf16(ahf[m], bhf[n], acc[m][n], 0, 0, 0);
                    acc[m][n] = __builtin_amdgcn_mfma_f32_16x16x32_bf16(alf[m], bhf[n], acc[m][n], 0, 0, 0);
                    acc[m][n] = __builtin_amdgcn_mfma_f32_16x16x32_bf16(ahf[m], blf[n], acc[m][n], 0, 0, 0);
                }
        }
    }

    #pragma unroll
    for (int n = 0; n < 4; ++n) {
        int c = col0 + wc * 64 + n * 16 + fr;
        float bv = bias ? bias[c] : 0.f;
        #pragma unroll
        for (int m = 0; m < 4; ++m) {
            int rbase = row0 + wr * 64 + m * 16 + fg * 4;
            #pragma unroll
            for (int i = 0; i < 4; ++i) {
                int r = rbase + i;
                if (r < M) {
                    float v = acc[m][n][i] + bv;
                    if (do_relu) v = fmaxf(v, 0.f);
                    unsigned short oh, ol;
                    f2hilo(v, oh, ol);
                    Ch[(size_t)r * N + c] = oh;
                    Cl[(size_t)r * N + c] = ol;
                }
            }
        }
    }
}

// ---------------- twin L1 + both rowdots, fused (plane inputs) ----------------
// s1[r] = dot( relu(X[r]@W + bias), P[r] );  s0[r] = dot(X[r], Q[r]);  X,P,Q are planes.
__global__ __launch_bounds__(256, 2) void gemm_rowdot_mfma(
    const unsigned short* __restrict__ XH, const unsigned short* __restrict__ XL,
    const unsigned short* __restrict__ Wh, const unsigned short* __restrict__ Wl,
    const float* __restrict__ bias,
    const unsigned short* __restrict__ PH, const unsigned short* __restrict__ PL,
    const unsigned short* __restrict__ QH, const unsigned short* __restrict__ QL,
    float* __restrict__ s0g, float* __restrict__ s1g, int M)
{
    __shared__ unsigned short Ah[128 * 32];
    __shared__ unsigned short Al[128 * 32];
    __shared__ unsigned short Bh[128 * 32];
    __shared__ unsigned short Bl[128 * 32];
    __shared__ float srow[128];
    __shared__ float s0buf[256];

    int tid = threadIdx.x;
    int lane = tid & 63;
    int w = tid >> 6;
    int wr = w >> 1, wc = w & 1;
    int row0 = blockIdx.x * 128;
    int fr = lane & 15;
    int fg = lane >> 4;

    int sr = tid >> 1;
    int sk = (tid & 1) * 16;
    int grow = row0 + sr; if (grow >= M) grow = M - 1;
    int wbase = ((sr >> 4) * 64 + (sk >> 3) * 16 + (sr & 15)) * 8;

    if (tid < 128) srow[tid] = 0.f;
    float s0part = 0.f;

    const unsigned short* Xh = XH + (size_t)grow * NFEAT;
    const unsigned short* Xl = XL + (size_t)grow * NFEAT;
    const unsigned short* Qh = QH + (size_t)grow * NFEAT;
    const unsigned short* Ql = QL + (size_t)grow * NFEAT;

    float rp[4][4];
    #pragma unroll
    for (int m = 0; m < 4; ++m)
        #pragma unroll
        for (int i = 0; i < 4; ++i) rp[m][i] = 0.f;

    for (int ct = 0; ct < 2; ++ct) {
        int col0 = ct * 128;
        const unsigned short* WhR = Wh + (size_t)(col0 + sr) * NFEAT;
        const unsigned short* WlR = Wl + (size_t)(col0 + sr) * NFEAT;

        f32x4 acc[4][4];
        #pragma unroll
        for (int m = 0; m < 4; ++m)
            #pragma unroll
            for (int n = 0; n < 4; ++n)
                acc[m][n] = (f32x4)(0.f);

        for (int k0 = 0; k0 < NFEAT; k0 += 32) {
            us8 ah0 = *(const us8*)(Xh + k0 + sk);
            us8 ah1 = *(const us8*)(Xh + k0 + sk + 8);
            us8 al0 = *(const us8*)(Xl + k0 + sk);
            us8 al1 = *(const us8*)(Xl + k0 + sk + 8);
            if (ct == 0) {
                us8 qh0 = *(const us8*)(Qh + k0 + sk);
                us8 qh1 = *(const us8*)(Qh + k0 + sk + 8);
                us8 ql0 = *(const us8*)(Ql + k0 + sk);
                us8 ql1 = *(const us8*)(Ql + k0 + sk + 8);
                #pragma unroll
                for (int j = 0; j < 8; ++j) {
                    float xv0 = bf2f((unsigned short)ah0[j]) + bf2f((unsigned short)al0[j]);
                    float qv0 = bf2f((unsigned short)qh0[j]) + bf2f((unsigned short)ql0[j]);
                    float xv1 = bf2f((unsigned short)ah1[j]) + bf2f((unsigned short)al1[j]);
                    float qv1 = bf2f((unsigned short)qh1[j]) + bf2f((unsigned short)ql1[j]);
                    s0part += xv0 * qv0 + xv1 * qv1;
                }
            }
            us8 bh0 = *(const us8*)(WhR + k0 + sk);
            us8 bh1 = *(const us8*)(WhR + k0 + sk + 8);
            us8 bl0 = *(const us8*)(WlR + k0 + sk);
            us8 bl1 = *(const us8*)(WlR + k0 + sk + 8);
            __syncthreads();
            *(us8*)&Ah[wbase]       = ah0;
            *(us8*)&Ah[wbase + 128] = ah1;
            *(us8*)&Al[wbase]       = al0;
            *(us8*)&Al[wbase + 128] = al1;
            *(us8*)&Bh[wbase]       = bh0;
            *(us8*)&Bh[wbase + 128] = bh1;
            *(us8*)&Bl[wbase]       = bl0;
            *(us8*)&Bl[wbase + 128] = bl1;
            __syncthreads();

            bf16x8 ahf[4], alf[4], bhf[4], blf[4];
            #pragma unroll
            for (int m = 0; m < 4; ++m) {
                int g = ((wr * 4 + m) * 64 + lane) * 8;
                ahf[m] = *(const bf16x8*)&Ah[g];
                alf[m] = *(const bf16x8*)&Al[g];
            }
            #pragma unroll
            for (int n = 0; n < 4; ++n) {
                int g = ((wc * 4 + n) * 64 + lane) * 8;
                bhf[n] = *(const bf16x8*)&Bh[g];
                blf[n] = *(const bf16x8*)&Bl[g];
            }
            #pragma unroll
            for (int m = 0; m < 4; ++m)
                #pragma unroll
                for (int n = 0; n < 4; ++n) {
                    acc[m][n] = __builtin_amdgcn_mfma_f32_16x16x32_bf16(ahf[m], bhf[n], acc[m][n], 0, 0, 0);
                    acc[m][n] = __builtin_amdgcn_mfma_f32_16x16x32_bf16(alf[m], bhf[n], acc[m][n], 0, 0, 0);
                    acc[m][n] = __builtin_amdgcn_mfma_f32_16x16x32_bf16(ahf[m], blf[n], acc[m][n], 0, 0, 0);
                }
        }

        // fold this col-half into the row dot-products (P reconstructed from planes)
        #pragma unroll
        for (int n = 0; n < 4; ++n) {
            int c = col0 + wc * 64 + n * 16 + fr;
            float bv = bias[c];
            #pragma unroll
            for (int m = 0; m < 4; ++m) {
                #pragma unroll
                for (int i = 0; i < 4; ++i) {
                    int r = row0 + wr * 64 + m * 16 + fg * 4 + i;
                    if (r < M) {
                        float v = fmaxf(acc[m][n][i] + bv, 0.f);
                        size_t o = (size_t)r * NFEAT + c;
                        float pv = bf2f(PH[o]) + bf2f(PL[o]);
                        rp[m][i] += v * pv;
                    }
                }
            }
        }
    }

    // s0: staging thread partials -> LDS combine (halves live in adjacent threads)
    s0buf[tid] = s0part;

    // s1: reduce rp over the 16 fr lanes
    #pragma unroll
    for (int o = 1; o < 16; o <<= 1) {
        #pragma unroll
        for (int m = 0; m < 4; ++m)
            #pragma unroll
            for (int i = 0; i < 4; ++i)
                rp[m][i] += __shfl_xor(rp[m][i], o);
    }
    if ((lane & 15) == 0) {
        #pragma unroll
        for (int m = 0; m < 4; ++m)
            #pragma unroll
            for (int i = 0; i < 4; ++i)
                atomicAdd(&srow[wr * 64 + m * 16 + fg * 4 + i], rp[m][i]);
    }
    __syncthreads();
    if (tid < 128 && row0 + tid < M) {
        s1g[row0 + tid] = srow[tid];
        s0g[row0 + tid] = s0buf[tid * 2] + s0buf[tid * 2 + 1];
    }
}

// ---------------- head GEMM with fused combine (plane inputs) ----------------
// logits = (a0*P1 + a1*P2) @ outW + outb ; N = 128
__global__ __launch_bounds__(256, 2) void gemm_head(
    const unsigned short* __restrict__ P1H, const unsigned short* __restrict__ P1L,
    const unsigned short* __restrict__ P2H, const unsigned short* __restrict__ P2L,
    const float* __restrict__ alpha,
    const unsigned short* __restrict__ Wh, const unsigned short* __restrict__ Wl,
    const float* __restrict__ bias,
    float* __restrict__ C, int M, int N)
{
    __shared__ unsigned short Ah[128 * 32];
    __shared__ unsigned short Al[128 * 32];
    __shared__ unsigned short Bh[128 * 32];
    __shared__ unsigned short Bl[128 * 32];

    int tid = threadIdx.x;
    int lane = tid & 63;
    int w = tid >> 6;
    int wr = w >> 1, wc = w & 1;
    int row0 = blockIdx.x * 128;
    int fr = lane & 15;
    int fg = lane >> 4;

    int sr = tid >> 1;
    int sk = (tid & 1) * 16;
    int grow = row0 + sr; if (grow >= M) grow = M - 1;
    int wbase = ((sr >> 4) * 64 + (sk >> 3) * 16 + (sr & 15)) * 8;

    const unsigned short* p1h = P1H + (size_t)grow * NFEAT;
    const unsigned short* p1l = P1L + (size_t)grow * NFEAT;
    const unsigned short* p2h = P2H + (size_t)grow * NFEAT;
    const unsigned short* p2l = P2L + (size_t)grow * NFEAT;
    float a0 = alpha[grow], a1 = alpha[M + grow];
    const unsigned short* WhR = Wh + (size_t)sr * NFEAT;
    const unsigned short* WlR = Wl + (size_t)sr * NFEAT;

    f32x4 acc[4][4];
    #pragma unroll
    for (int m = 0; m < 4; ++m)
        #pragma unroll
        for (int n = 0; n < 4; ++n)
            acc[m][n] = (f32x4)(0.f);

    for (int k0 = 0; k0 < NFEAT; k0 += 32) {
        us8 uh0 = *(const us8*)(p1h + k0 + sk);
        us8 uh1 = *(const us8*)(p1h + k0 + sk + 8);
        us8 ul0 = *(const us8*)(p1l + k0 + sk);
        us8 ul1 = *(const us8*)(p1l + k0 + sk + 8);
        us8 vh0 = *(const us8*)(p2h + k0 + sk);
        us8 vh1 = *(const us8*)(p2h + k0 + sk + 8);
        us8 vl0 = *(const us8*)(p2l + k0 + sk);
        us8 vl1 = *(const us8*)(p2l + k0 + sk + 8);
        unsigned short hh[16], ll[16];
        #pragma unroll
        for (int j = 0; j < 8; ++j) {
            float u0 = bf2f((unsigned short)uh0[j]) + bf2f((unsigned short)ul0[j]);
            float v0 = bf2f((unsigned short)vh0[j]) + bf2f((unsigned short)vl0[j]);
            f2hilo(a0 * u0 + a1 * v0, hh[j], ll[j]);
            float u1 = bf2f((unsigned short)uh1[j]) + bf2f((unsigned short)ul1[j]);
            float v1 = bf2f((unsigned short)vh1[j]) + bf2f((unsigned short)vl1[j]);
            f2hilo(a0 * u1 + a1 * v1, hh[8 + j], ll[8 + j]);
        }
        us8 bh0 = *(const us8*)(WhR + k0 + sk);
        us8 bh1 = *(const us8*)(WhR + k0 + sk + 8);
        us8 bl0 = *(const us8*)(WlR + k0 + sk);
        us8 bl1 = *(const us8*)(WlR + k0 + sk + 8);
        __syncthreads();
        *(us8*)&Ah[wbase]       = *(us8*)&hh[0];
        *(us8*)&Ah[wbase + 128] = *(us8*)&hh[8];
        *(us8*)&Al[wbase]       = *(us8*)&ll[0];
        *(us8*)&Al[wbase + 128] = *(us8*)&ll[8];
        *(us8*)&Bh[wbase]       = bh0;
        *(us8*)&Bh[wbase + 128] = bh1;
        *(us8*)&Bl[wbase]       = bl0;
        *(us8*)&Bl[wbase + 128] = bl1;
        __syncthreads();

        bf16x8 ahf[4], alf[4], bhf[4], blf[4];
        #pragma unroll
        for (int m = 0; m < 4; ++m) {
            int g = ((wr * 4 + m) * 64 + lane) * 8;
            ahf[m] = *(const bf16x8*)&Ah[g];
            alf[m] = *(const bf16x8*)&Al[g];
        }
        #pragma unroll
        for (int n = 0; n < 4; ++n) {
            int g = ((wc * 4 + n) * 64 + lane) * 8;
            bhf[n] = *(const bf16x8*)&Bh[g];
            blf[n] = *(const bf16x8*)&Bl[g];
        }
        #pragma unroll
        for (int m = 0; m < 4; ++m)
            #pragma unroll
            for (int n = 0; n < 4; ++n) {
                acc[m][n] = __builtin_amdgcn_mfma_f32_16x16x32_bf16(ahf[m], bhf[n], acc[m][n], 0, 0, 0);
                acc[m][n] = __builtin_amdgcn_mfma_f32_16x16x32_bf16(alf[m], bhf[n], acc[m][n], 0, 0, 0);
                acc[m][n] = __builtin_amdgcn_mfma_f32_16x16x32_bf16(ahf[m], blf[n], acc[m][n], 0, 0, 0);
            }
    }

    #pragma unroll
    for (int n = 0; n < 4; ++n) {
        int c = wc * 64 + n * 16 + fr;
        if (c >= N) continue;
        float bv = bias[c];
        #pragma unroll
        for (int m = 0; m < 4; ++m) {
            int rbase = row0 + wr * 64 + m * 16 + fg * 4;
            #pragma unroll
            for (int i = 0; i < 4; ++i) {
                int r = rbase + i;
                if (r < M) C[(size_t)r * N + c] = acc[m][n][i] + bv;
            }
        }
    }
}

extern "C" void kernel_launch(void* const* d_in, const int* in_sizes, int n_in,
                              void* d_out, int out_size, void* d_ws, size_t ws_size,
                              hipStream_t stream)
{
    const float* x_paper    = (const float*)d_in[0];
    const float* emb_author = (const float*)d_in[1];
    const float* W0rp = (const float*)d_in[2];
    const float* b0rp = (const float*)d_in[3];
    const float* W0ra = (const float*)d_in[4];
    const float* b0ra = (const float*)d_in[5];
    const float* W0w  = (const float*)d_in[6];
    const float* W0rev= (const float*)d_in[7];
    const float* W0c  = (const float*)d_in[8];
    const float* W1rp = (const float*)d_in[9];
    const float* b1rp = (const float*)d_in[10];
    const float* W1w  = (const float*)d_in[13];
    const float* W1c  = (const float*)d_in[15];
    const float* outW = (const float*)d_in[16];
    const float* outb = (const float*)d_in[17];
    const int* w_src = (const int*)d_in[18];
    const int* w_dst = (const int*)d_in[19];
    const int* r_src = (const int*)d_in[20];
    const int* r_dst = (const int*)d_in[21];
    const int* c_src = (const int*)d_in[22];
    const int* c_dst = (const int*)d_in[23];

    const int NP = in_sizes[0] / NFEAT;   // 50000
    const int NA = in_sizes[1] / NFEAT;   // 50000
    const int NC = in_sizes[17];          // 128
    const int nEw = in_sizes[18], nEr = in_sizes[20], nEc = in_sizes[22];

    // ---- workspace (~164 MB): 3 plane-pair slots (same bytes as fp32) + weights + CSR ----
    size_t NB = (size_t)(NP > NA ? NP : NA) * NFEAT;   // elems per plane
    unsigned short* Zb = (unsigned short*)d_ws;
    #define ZH(i) (Zb + (size_t)(i) * 2 * NB)
    #define ZL(i) (ZH(i) + NB)
    float* s0 = (float*)(Zb + 6 * NB);   // NP
    float* s1 = s0 + NP;                 // NP
    unsigned short* Wt = (unsigned short*)(s1 + NP);   // 11 slots x 131072 ushorts
    #define WT_HI(i) (Wt + (size_t)(i) * 131072)
    #define WT_LO(i) (Wt + (size_t)(i) * 131072 + 65536)
    int* degW = (int*)(Wt + 11 * 131072);
    int* degR = degW + NP;
    int* degC = degR + NA;
    int* curW = degC + NP;
    int* curR = curW + NP;
    int* curC = curR + NA;
    int* offW = curC + NP;          // NP+1
    int* offR = offW + NP + 1;      // NA+1
    int* offC = offR + NA + 1;      // NP+1
    int* bsW  = offC + NP + 1;      // 256
    int* bsR  = bsW + 256;
    int* bsC  = bsR + 256;
    int* listW = bsC + 256;         // nEw
    int* listR = listW + nEw;       // nEr
    int* listC = listR + nEr;       // nEc

    float* out   = (float*)d_out;                 // logits [NP, NC]
    float* alpha = out + (size_t)NP * NC;         // [2, NP]

    // ---- CSR build ----
    hipMemsetAsync(degW, 0, (size_t)2 * (NP + NA + NP) * sizeof(int), stream);
    deg_int_kernel<<<(nEw + 255) / 256, 256, 0, stream>>>(w_dst, degW, nEw);
    deg_int_kernel<<<(nEr + 255) / 256, 256, 0, stream>>>(r_dst, degR, nEr);
    deg_int_kernel<<<(nEc + 255) / 256, 256, 0, stream>>>(c_dst, degC, nEc);

    int nbP = (NP + 255) / 256, nbA = (NA + 255) / 256;
    scan_p1<<<nbP, 256, 0, stream>>>(degW, NP, offW, bsW);
    scan_p1<<<nbA, 256, 0, stream>>>(degR, NA, offR, bsR);
    scan_p1<<<nbP, 256, 0, stream>>>(degC, NP, offC, bsC);
    scan_p2<<<3, 256, 0, stream>>>(bsW, nbP, bsR, nbA, bsC, nbP);
    scan_p3<<<nbP, 256, 0, stream>>>(NP, offW, bsW);
    scan_p3<<<nbA, 256, 0, stream>>>(NA, offR, bsR);
    scan_p3<<<nbP, 256, 0, stream>>>(NP, offC, bsC);

    fill_csr_kernel<<<(nEw + 255) / 256, 256, 0, stream>>>(w_src, w_dst, nEw, offW, curW, listW);
    fill_csr_kernel<<<(nEr + 255) / 256, 256, 0, stream>>>(r_src, r_dst, nEr, offR, curR, listR);
    fill_csr_kernel<<<(nEc + 255) / 256, 256, 0, stream>>>(c_src, c_dst, nEc, offC, curC, listC);

    // ---- weight conversion ([N][K] split planes) ----
    cvt8_kernel<<<dim3(256, 8), 256, 0, stream>>>(W0rp, W0w, W0c, W0ra, W0rev, W1rp, W1w, W1c, Wt);
    cvtfold_kernel<<<dim3(256, 2), 256, 0, stream>>>(W0rp, W0w, W0c, W1rp, W1w, W1c, Wt);
    cvtrect_kernel<<<128, 256, 0, stream>>>(outW, Wt);

    dim3 blk(256);
    dim3 gP((NP + 127) / 128, 2);     // N=256
    dim3 gA((NA + 127) / 128, 2);
    dim3 g1((NP + 127) / 128);
    int nodeP = (NP + 3) / 4, nodeA = (NA + 3) / 4;

    SegA nul = {nullptr, nullptr, nullptr, nullptr, nullptr};

    // --- L0: aggregate raw features, then one fused GEMM per node type ---
    agg_csr<<<nodeP, blk, 0, stream>>>(emb_author, nullptr, nullptr, offW, listW,
                                       nullptr, nullptr, ZH(0), ZL(0), 0, NP);   // Mw -> slot0
    agg_csr<<<nodeP, blk, 0, stream>>>(x_paper, nullptr, nullptr, offC, listC,
                                       nullptr, nullptr, ZH(1), ZL(1), 0, NP);   // Mc -> slot1
    {   // P1 = relu([Xp|Mw|Mc] @ [W0rp;W0w;W0c] + b0rp) -> slot2
        SegA a0 = {x_paper, nullptr, nullptr, WT_HI(0), WT_LO(0)};
        SegA a1 = {nullptr, ZH(0), ZL(0), WT_HI(1), WT_LO(1)};
        SegA a2 = {nullptr, ZH(1), ZL(1), WT_HI(2), WT_LO(2)};
        gemm_ms<<<gP, blk, 0, stream>>>(a0, a1, a2, 3, b0rp, 1, ZH(2), ZL(2), NP, NFEAT);
    }
    agg_csr<<<nodeA, blk, 0, stream>>>(x_paper, nullptr, nullptr, offR, listR,
                                       nullptr, nullptr, ZH(0), ZL(0), 0, NA);   // Mr -> slot0
    {   // Au1 = relu([Xa|Mr] @ [W0ra;W0rev] + b0ra) -> slot1
        SegA a0 = {emb_author, nullptr, nullptr, WT_HI(3), WT_LO(3)};
        SegA a1 = {nullptr, ZH(0), ZL(0), WT_HI(4), WT_LO(4)};
        gemm_ms<<<gA, blk, 0, stream>>>(a0, a1, nul, 2, b0ra, 1, ZH(1), ZL(1), NA, NFEAT);
    }

    // --- L1 paper ---
    agg_csr<<<nodeP, blk, 0, stream>>>(nullptr, ZH(1), ZL(1), offW, listW,
                                       nullptr, nullptr, ZH(0), ZL(0), 0, NP);   // Mw2 = mean_w(Au1) -> slot0
    {   // P2pre = [P1|Mw2] @ [W1rp;W1w] + b1rp -> slot1 (Au1 consumed)
        SegA a0 = {nullptr, ZH(2), ZL(2), WT_HI(5), WT_LO(5)};
        SegA a1 = {nullptr, ZH(0), ZL(0), WT_HI(6), WT_LO(6)};
        gemm_ms<<<gP, blk, 0, stream>>>(a0, a1, nul, 2, b1rp, 0, ZH(1), ZL(1), NP, NFEAT);
    }
    {   // T = P1 @ W1c -> slot0 (Mw2 consumed)
        SegA a0 = {nullptr, ZH(2), ZL(2), WT_HI(7), WT_LO(7)};
        gemm_ms<<<gP, blk, 0, stream>>>(a0, nul, nul, 1, nullptr, 0, ZH(0), ZL(0), NP, NFEAT);
    }
    // P2 = relu(P2pre + mean_c(T)) -> slot1 (in place)
    agg_csr<<<nodeP, blk, 0, stream>>>(nullptr, ZH(0), ZL(0), offC, listC,
                                       ZH(1), ZL(1), ZH(1), ZL(1), 1, NP);

    // --- twin path + rowdots ---
    {   // P1t = relu(Xp @ Wc0 + b0rp) -> slot0 (T consumed)
        SegA a0 = {x_paper, nullptr, nullptr, WT_HI(8), WT_LO(8)};
        gemm_ms<<<gP, blk, 0, stream>>>(a0, nul, nul, 1, b0rp, 1, ZH(0), ZL(0), NP, NFEAT);
    }
    // s1 = P2 . relu(P1t@Wc1+b1rp) ; s0 = P1 . P1t
    gemm_rowdot_mfma<<<g1, blk, 0, stream>>>(ZH(0), ZL(0), WT_HI(9), WT_LO(9), b1rp,
                                             ZH(1), ZL(1), ZH(2), ZL(2), s0, s1, NP);

    // --- summarize + head ---
    alpha_kernel<<<(NP + 255) / 256, blk, 0, stream>>>(s0, s1, alpha, NP);
    gemm_head<<<g1, blk, 0, stream>>>(ZH(2), ZL(2), ZH(1), ZL(1), alpha,
                                      WT_HI(10), WT_LO(10), outb, out, NP, NC);
}